// Round 2
// baseline (395.015 us; speedup 1.0000x reference)
//
#include <hip/hip_runtime.h>

#define D 16
#define NODES_PER_BLOCK 16

// ---------------- CSR build: counting sort of edges by v ----------------

// Histogram of v into cnt[] (cnt pre-zeroed via hipMemsetAsync).
__global__ __launch_bounds__(256) void hist_kernel(const int* __restrict__ v,
                                                   int* __restrict__ cnt, int E) {
    int e = blockIdx.x * 256 + threadIdx.x;
    if (e < E) atomicAdd(&cnt[v[e]], 1);
}

// Per-block exclusive scan over 1024 elements (in place), block totals to bsum.
__global__ __launch_bounds__(256) void scan1_kernel(int* __restrict__ a,
                                                    int* __restrict__ bsum, int n) {
    __shared__ int wsum[4];
    int t = threadIdx.x;
    int base = blockIdx.x * 1024 + t * 4;
    int c0 = (base + 0 < n) ? a[base + 0] : 0;
    int c1 = (base + 1 < n) ? a[base + 1] : 0;
    int c2 = (base + 2 < n) ? a[base + 2] : 0;
    int c3 = (base + 3 < n) ? a[base + 3] : 0;
    int tsum = c0 + c1 + c2 + c3;
    int lane = t & 63, wid = t >> 6;
    int incl = tsum;
    for (int d = 1; d < 64; d <<= 1) {
        int m = __shfl_up(incl, d, 64);
        if (lane >= d) incl += m;
    }
    if (lane == 63) wsum[wid] = incl;
    __syncthreads();
    if (t == 0) {
        int s = 0;
        for (int k = 0; k < 4; k++) { int tmp = wsum[k]; wsum[k] = s; s += tmp; }
        bsum[blockIdx.x] = s;
    }
    __syncthreads();
    int excl = incl - tsum + wsum[wid];
    if (base + 0 < n) a[base + 0] = excl;
    if (base + 1 < n) a[base + 1] = excl + c0;
    if (base + 2 < n) a[base + 2] = excl + c0 + c1;
    if (base + 3 < n) a[base + 3] = excl + c0 + c1 + c2;
}

// Serial exclusive scan of the (<=256) block sums.
__global__ void scan2_kernel(int* __restrict__ bsum, int nb) {
    if (threadIdx.x == 0 && blockIdx.x == 0) {
        int s = 0;
        for (int b = 0; b < nb; b++) { int t = bsum[b]; bsum[b] = s; s += t; }
    }
}

// Add back block offsets; duplicate into cursor array; write sentinel off[n]=E.
__global__ __launch_bounds__(256) void scan3_kernel(int* __restrict__ off,
                                                    int* __restrict__ cur,
                                                    const int* __restrict__ bsum,
                                                    int n, int E) {
    int idx = blockIdx.x * 256 + threadIdx.x;
    if (idx < n) {
        int val = off[idx] + bsum[idx >> 10];
        off[idx] = val;
        cur[idx] = val;
    }
    if (idx == 0) off[n] = E;
}

// Scatter edge payloads (u, widx) into v-sorted order.
__global__ __launch_bounds__(256) void scatter_kernel(const int* __restrict__ u,
                                                      const int* __restrict__ v,
                                                      const int* __restrict__ widx,
                                                      int* __restrict__ cur,
                                                      int* __restrict__ su,
                                                      int* __restrict__ sw, int E) {
    int e = blockIdx.x * 256 + threadIdx.x;
    if (e >= E) return;
    int pos = atomicAdd(&cur[v[e]], 1);
    su[pos] = u[e];
    sw[pos] = widx[e];
}

// ---------------- Gather-compute: 16 lanes per node, no output atomics ----

__global__ __launch_bounds__(256) void gather_kernel(const float* __restrict__ x,
                                                     const float* __restrict__ W,
                                                     const int* __restrict__ off,
                                                     const int* __restrict__ su,
                                                     const int* __restrict__ sw,
                                                     float* __restrict__ out, int N) {
    int t = threadIdx.x;
    int o = t & 15;
    int node = blockIdx.x * NODES_PER_BLOCK + (t >> 4);
    if (node >= N) return;
    int start = off[node], end = off[node + 1];
    float acc = 0.0f;
    for (int j = start; j < end; j++) {
        int w  = sw[j];
        int uu = su[j];
        const float* Wr = W + (size_t)w * (D * D) + o * D;
        float4 w0 = *(const float4*)(Wr + 0);
        float4 w1 = *(const float4*)(Wr + 4);
        float4 w2 = *(const float4*)(Wr + 8);
        float4 w3 = *(const float4*)(Wr + 12);
        float xv = x[uu * D + o];
        acc += w0.x * __shfl(xv,  0, 16);
        acc += w0.y * __shfl(xv,  1, 16);
        acc += w0.z * __shfl(xv,  2, 16);
        acc += w0.w * __shfl(xv,  3, 16);
        acc += w1.x * __shfl(xv,  4, 16);
        acc += w1.y * __shfl(xv,  5, 16);
        acc += w1.z * __shfl(xv,  6, 16);
        acc += w1.w * __shfl(xv,  7, 16);
        acc += w2.x * __shfl(xv,  8, 16);
        acc += w2.y * __shfl(xv,  9, 16);
        acc += w2.z * __shfl(xv, 10, 16);
        acc += w2.w * __shfl(xv, 11, 16);
        acc += w3.x * __shfl(xv, 12, 16);
        acc += w3.y * __shfl(xv, 13, 16);
        acc += w3.z * __shfl(xv, 14, 16);
        acc += w3.w * __shfl(xv, 15, 16);
    }
    out[node * D + o] = fmaxf(acc, 0.0f);
}

// ---------------- Fallback path (round-1 kernel) if workspace too small ----

__global__ __launch_bounds__(256) void edge_scatter_kernel(
    const float* __restrict__ x, const float* __restrict__ W,
    const int* __restrict__ u, const int* __restrict__ v,
    const int* __restrict__ widx, float* __restrict__ out, int E) {
    int tid = blockIdx.x * 256 + threadIdx.x;
    int e = tid >> 4;
    int o = tid & 15;
    if (e >= E) return;
    int w = widx[e], uu = u[e], vv = v[e];
    const float* Wr = W + (size_t)w * (D * D) + o * D;
    float4 w0 = *(const float4*)(Wr + 0);
    float4 w1 = *(const float4*)(Wr + 4);
    float4 w2 = *(const float4*)(Wr + 8);
    float4 w3 = *(const float4*)(Wr + 12);
    float xv = x[uu * D + o];
    float acc = 0.0f;
    acc += w0.x * __shfl(xv, 0, 16);  acc += w0.y * __shfl(xv, 1, 16);
    acc += w0.z * __shfl(xv, 2, 16);  acc += w0.w * __shfl(xv, 3, 16);
    acc += w1.x * __shfl(xv, 4, 16);  acc += w1.y * __shfl(xv, 5, 16);
    acc += w1.z * __shfl(xv, 6, 16);  acc += w1.w * __shfl(xv, 7, 16);
    acc += w2.x * __shfl(xv, 8, 16);  acc += w2.y * __shfl(xv, 9, 16);
    acc += w2.z * __shfl(xv, 10, 16); acc += w2.w * __shfl(xv, 11, 16);
    acc += w3.x * __shfl(xv, 12, 16); acc += w3.y * __shfl(xv, 13, 16);
    acc += w3.z * __shfl(xv, 14, 16); acc += w3.w * __shfl(xv, 15, 16);
    atomicAdd(out + (size_t)vv * D + o, acc);
}

__global__ __launch_bounds__(256) void relu_kernel(float* __restrict__ out, int n4) {
    int i = blockIdx.x * 256 + threadIdx.x;
    if (i >= n4) return;
    float4* p = (float4*)out + i;
    float4 val = *p;
    val.x = fmaxf(val.x, 0.0f); val.y = fmaxf(val.y, 0.0f);
    val.z = fmaxf(val.z, 0.0f); val.w = fmaxf(val.w, 0.0f);
    *p = val;
}

extern "C" void kernel_launch(void* const* d_in, const int* in_sizes, int n_in,
                              void* d_out, int out_size, void* d_ws, size_t ws_size,
                              hipStream_t stream) {
    const float* x    = (const float*)d_in[0];
    const float* W    = (const float*)d_in[1];
    const int*   u    = (const int*)d_in[2];
    const int*   v    = (const int*)d_in[3];
    const int*   widx = (const int*)d_in[4];
    float* out = (float*)d_out;

    int E = in_sizes[2];
    int N = out_size / D;

    // Workspace layout
    int* off  = (int*)d_ws;        // N+1
    int* cur  = off + (N + 1);     // N
    int* bsum = cur + N;           // <=256
    int* su   = bsum + 256;        // E
    int* sw   = su + E;            // E
    size_t needed = ((size_t)(N + 1) + N + 256 + 2 * (size_t)E) * sizeof(int);

    if (ws_size < needed) {
        // Fallback: atomic scatter path.
        hipMemsetAsync(d_out, 0, (size_t)out_size * sizeof(float), stream);
        int total = E * 16;
        edge_scatter_kernel<<<(total + 255) / 256, 256, 0, stream>>>(x, W, u, v, widx, out, E);
        int n4 = out_size / 4;
        relu_kernel<<<(n4 + 255) / 256, 256, 0, stream>>>(out, n4);
        return;
    }

    int NB = (N + 1023) / 1024;  // scan blocks (98 for N=100000)

    hipMemsetAsync(off, 0, (size_t)(N + 1) * sizeof(int), stream);
    hist_kernel<<<(E + 255) / 256, 256, 0, stream>>>(v, off, E);
    scan1_kernel<<<NB, 256, 0, stream>>>(off, bsum, N);
    scan2_kernel<<<1, 64, 0, stream>>>(bsum, NB);
    scan3_kernel<<<(N + 255) / 256, 256, 0, stream>>>(off, cur, bsum, N, E);
    scatter_kernel<<<(E + 255) / 256, 256, 0, stream>>>(u, v, widx, cur, su, sw, E);

    int gblocks = (N + NODES_PER_BLOCK - 1) / NODES_PER_BLOCK;
    gather_kernel<<<gblocks, 256, 0, stream>>>(x, W, off, su, sw, out, N);
}